// Round 1
// baseline (4141.141 us; speedup 1.0000x reference)
//
#include <hip/hip_runtime.h>
#include <hip/hip_bf16.h>
#include <math.h>

#define B 4
#define N 1024
#define DM 512
#define H 8
#define DH 64
#define MLP 2048
#define TOK (B * N)
#define QKVW (3 * DM)
#define EPS 1e-5f
#define SCALE 0.125f

// ---------------- LayerNorm over last dim (512) ----------------
__global__ __launch_bounds__(256) void ln_kernel(const float* __restrict__ x,
                                                 const float* __restrict__ g,
                                                 const float* __restrict__ bta,
                                                 float* __restrict__ out) {
    const int row = blockIdx.x;
    const int t = threadIdx.x;
    const float* xr = x + (size_t)row * DM;
    float v0 = xr[t], v1 = xr[t + 256];
    float s = v0 + v1, ss = v0 * v0 + v1 * v1;
    for (int o = 32; o; o >>= 1) {
        s += __shfl_down(s, o);
        ss += __shfl_down(ss, o);
    }
    __shared__ float ls[4], lss[4];
    const int wid = t >> 6, lane = t & 63;
    if (lane == 0) { ls[wid] = s; lss[wid] = ss; }
    __syncthreads();
    if (t == 0) {
        float S = ls[0] + ls[1] + ls[2] + ls[3];
        float SS = lss[0] + lss[1] + lss[2] + lss[3];
        float mu = S / DM;
        ls[0] = mu;
        lss[0] = SS / DM - mu * mu;
    }
    __syncthreads();
    const float mu = ls[0];
    const float r = rsqrtf(lss[0] + EPS);
    out[(size_t)row * DM + t]       = (v0 - mu) * r * g[t] + bta[t];
    out[(size_t)row * DM + t + 256] = (v1 - mu) * r * g[t + 256] + bta[t + 256];
}

// ---------------- Generic tiled GEMM: C = A[M,K] @ W[K,N] (+epilogue) ------
// EP: 0 = none, 2 = bias+gelu, 3 = bias+residual, 4 = bias+residual+tanh
template <int EP>
__global__ __launch_bounds__(256) void gemm_kernel(const float* __restrict__ A,
                                                   const float* __restrict__ W,
                                                   const float* __restrict__ bias,
                                                   const float* __restrict__ res,
                                                   float* __restrict__ C,
                                                   int M, int Nn, int K) {
    __shared__ float As[16][64 + 1];
    __shared__ float Bs[16][64];
    const int t = threadIdx.x;
    const int tx = t & 15, ty = t >> 4;
    const int m0 = blockIdx.y * 64, n0 = blockIdx.x * 64;
    float c[4][4] = {};
    for (int kt = 0; kt < K; kt += 16) {
#pragma unroll
        for (int u = 0; u < 4; ++u) {
            int idx = t + u * 256;
            int mm = idx >> 4, kk = idx & 15;
            As[kk][mm] = A[(size_t)(m0 + mm) * K + kt + kk];
        }
#pragma unroll
        for (int u = 0; u < 4; ++u) {
            int idx = t + u * 256;
            int kk = idx >> 6, nn = idx & 63;
            Bs[kk][nn] = W[(size_t)(kt + kk) * Nn + n0 + nn];
        }
        __syncthreads();
#pragma unroll
        for (int kk = 0; kk < 16; ++kk) {
            float av[4], bv[4];
#pragma unroll
            for (int i = 0; i < 4; ++i) av[i] = As[kk][ty * 4 + i];
#pragma unroll
            for (int j = 0; j < 4; ++j) bv[j] = Bs[kk][tx * 4 + j];
#pragma unroll
            for (int i = 0; i < 4; ++i)
#pragma unroll
                for (int j = 0; j < 4; ++j) c[i][j] = fmaf(av[i], bv[j], c[i][j]);
        }
        __syncthreads();
    }
#pragma unroll
    for (int i = 0; i < 4; ++i) {
        const int row = m0 + ty * 4 + i;
#pragma unroll
        for (int j = 0; j < 4; ++j) {
            const int col = n0 + tx * 4 + j;
            float v = c[i][j];
            if (EP >= 2) v += bias[col];
            if (EP == 2) v = 0.5f * v * (1.0f + erff(v * 0.70710678118654752f));
            if (EP == 3) v += res[(size_t)row * Nn + col];
            if (EP == 4) { v += res[(size_t)row * Nn + col]; v = tanhf(v); }
            C[(size_t)row * Nn + col] = v;
        }
    }
}

// ---------------- QK^T per (b,h): dots[i,j] = scale * q_i . k_j ------------
__global__ __launch_bounds__(256) void qk_kernel(const float* __restrict__ qkv,
                                                 float* __restrict__ attn, int b) {
    const int h = blockIdx.z;
    const int i0 = blockIdx.y * 64, j0 = blockIdx.x * 64;
    const int t = threadIdx.x;
    const int tx = t & 15, ty = t >> 4;
    __shared__ float Qs[64][65], Ks[64][65];
#pragma unroll
    for (int u = 0; u < 16; ++u) {
        int idx = t + u * 256;
        int r = idx >> 6, d = idx & 63;
        Qs[r][d] = qkv[(size_t)(b * N + i0 + r) * QKVW + h * 64 + d];
        Ks[r][d] = qkv[(size_t)(b * N + j0 + r) * QKVW + DM + h * 64 + d];
    }
    __syncthreads();
    float c[4][4] = {};
#pragma unroll
    for (int kk = 0; kk < 64; ++kk) {
        float av[4], bv[4];
#pragma unroll
        for (int i = 0; i < 4; ++i) av[i] = Qs[ty * 4 + i][kk];
#pragma unroll
        for (int j = 0; j < 4; ++j) bv[j] = Ks[tx * 4 + j][kk];
#pragma unroll
        for (int i = 0; i < 4; ++i)
#pragma unroll
            for (int j = 0; j < 4; ++j) c[i][j] = fmaf(av[i], bv[j], c[i][j]);
    }
#pragma unroll
    for (int i = 0; i < 4; ++i)
#pragma unroll
        for (int j = 0; j < 4; ++j)
            attn[(size_t)(h * N + i0 + ty * 4 + i) * N + j0 + tx * 4 + j] =
                c[i][j] * SCALE;
}

// ------- fused: per-row softmax (per head) + cross-head mix + head-LN ------
// One block per row i; attn is the per-batch [H][N][N] buffer, updated in place.
__global__ __launch_bounds__(256) void softmax_mix_kernel(float* __restrict__ attn,
                                                          const float* __restrict__ rw,
                                                          const float* __restrict__ rg,
                                                          const float* __restrict__ rb) {
    const int i = blockIdx.x;
    const int t = threadIdx.x;
    const int lane = t & 63, wid = t >> 6;
    __shared__ float red[4];
    __shared__ float srw[64], srg[8], srb[8];
    if (t < 64) srw[t] = rw[t];
    if (t < 8) { srg[t] = rg[t]; srb[t] = rb[t]; }
    float p[8][4];
    for (int h = 0; h < 8; ++h) {
        float* rowp = attn + (size_t)(h * N + i) * N;
        float lm = -1e30f;
#pragma unroll
        for (int u = 0; u < 4; ++u) {
            p[h][u] = rowp[t + u * 256];
            lm = fmaxf(lm, p[h][u]);
        }
        for (int o = 32; o; o >>= 1) lm = fmaxf(lm, __shfl_down(lm, o));
        __syncthreads();
        if (lane == 0) red[wid] = lm;
        __syncthreads();
        const float M = fmaxf(fmaxf(red[0], red[1]), fmaxf(red[2], red[3]));
        float ls = 0.f;
#pragma unroll
        for (int u = 0; u < 4; ++u) {
            p[h][u] = expf(p[h][u] - M);
            ls += p[h][u];
        }
        for (int o = 32; o; o >>= 1) ls += __shfl_down(ls, o);
        __syncthreads();
        if (lane == 0) red[wid] = ls;
        __syncthreads();
        const float inv = 1.0f / (red[0] + red[1] + red[2] + red[3]);
#pragma unroll
        for (int u = 0; u < 4; ++u) p[h][u] *= inv;
    }
#pragma unroll
    for (int u = 0; u < 4; ++u) {
        float mg[8];
#pragma unroll
        for (int g = 0; g < 8; ++g) {
            float acc = 0.f;
#pragma unroll
            for (int h = 0; h < 8; ++h) acc += p[h][u] * srw[h * 8 + g];
            mg[g] = acc;
        }
        float mean = 0.f;
#pragma unroll
        for (int g = 0; g < 8; ++g) mean += mg[g];
        mean *= 0.125f;
        float var = 0.f;
#pragma unroll
        for (int g = 0; g < 8; ++g) { float d = mg[g] - mean; var += d * d; }
        var *= 0.125f;
        const float rs = rsqrtf(var + EPS);
#pragma unroll
        for (int g = 0; g < 8; ++g)
            attn[(size_t)(g * N + i) * N + t + u * 256] =
                (mg[g] - mean) * rs * srg[g] + srb[g];
    }
}

// ---------------- PV per (b,h): out[i,d] = sum_j P[i,j] * v[j,d] -----------
__global__ __launch_bounds__(256) void pv_kernel(const float* __restrict__ attn,
                                                 const float* __restrict__ qkv,
                                                 float* __restrict__ ao, int b) {
    const int h = blockIdx.y;
    const int i0 = blockIdx.x * 64;
    const int t = threadIdx.x;
    const int tx = t & 15, ty = t >> 4;
    __shared__ float Ps[16][64 + 1];
    __shared__ float Vs[16][64];
    float c[4][4] = {};
    for (int jt = 0; jt < N; jt += 16) {
#pragma unroll
        for (int u = 0; u < 4; ++u) {
            int idx = t + u * 256;
            int mm = idx >> 4, kk = idx & 15;
            Ps[kk][mm] = attn[(size_t)(h * N + i0 + mm) * N + jt + kk];
        }
#pragma unroll
        for (int u = 0; u < 4; ++u) {
            int idx = t + u * 256;
            int kk = idx >> 6, dd = idx & 63;
            Vs[kk][dd] = qkv[(size_t)(b * N + jt + kk) * QKVW + 2 * DM + h * 64 + dd];
        }
        __syncthreads();
#pragma unroll
        for (int kk = 0; kk < 16; ++kk) {
            float av[4], bv[4];
#pragma unroll
            for (int i = 0; i < 4; ++i) av[i] = Ps[kk][ty * 4 + i];
#pragma unroll
            for (int j = 0; j < 4; ++j) bv[j] = Vs[kk][tx * 4 + j];
#pragma unroll
            for (int i = 0; i < 4; ++i)
#pragma unroll
                for (int j = 0; j < 4; ++j) c[i][j] = fmaf(av[i], bv[j], c[i][j]);
        }
        __syncthreads();
    }
#pragma unroll
    for (int i = 0; i < 4; ++i)
#pragma unroll
        for (int j = 0; j < 4; ++j)
            ao[(size_t)(b * N + i0 + ty * 4 + i) * DM + h * 64 + tx * 4 + j] = c[i][j];
}

extern "C" void kernel_launch(void* const* d_in, const int* in_sizes, int n_in,
                              void* d_out, int out_size, void* d_ws, size_t ws_size,
                              hipStream_t stream) {
    const float* x_in   = (const float*)d_in[0];
    const float* ln1_g  = (const float*)d_in[1];
    const float* ln1_b  = (const float*)d_in[2];
    const float* w_qkv  = (const float*)d_in[3];
    const float* re_w   = (const float*)d_in[4];
    const float* rln_g  = (const float*)d_in[5];
    const float* rln_b  = (const float*)d_in[6];
    const float* w_out  = (const float*)d_in[7];
    const float* b_out  = (const float*)d_in[8];
    const float* ln2_g  = (const float*)d_in[9];
    const float* ln2_b  = (const float*)d_in[10];
    const float* w1     = (const float*)d_in[11];
    const float* b1     = (const float*)d_in[12];
    const float* w2     = (const float*)d_in[13];
    const float* b2     = (const float*)d_in[14];

    float* ws = (float*)d_ws;
    float* X    = ws;                          // TOK*DM        = 2,097,152
    float* HN   = X + (size_t)TOK * DM;        // TOK*DM        = 2,097,152
    float* QKV  = HN + (size_t)TOK * DM;       // TOK*3*DM      = 6,291,456
    float* AO   = QKV + (size_t)TOK * 3 * DM;  // TOK*DM        = 2,097,152
    float* SCR  = AO + (size_t)TOK * DM;       // max(H*N*N, TOK*MLP) = 8,388,608
    float* ATTN = SCR;                         // per-batch attn [H][N][N]
    float* HID  = SCR;                         // ffn hidden [TOK][MLP]

    hipMemcpyAsync(X, x_in, sizeof(float) * (size_t)TOK * DM,
                   hipMemcpyDeviceToDevice, stream);

    for (int l = 0; l < 4; ++l) {
        // ---- attention ----
        ln_kernel<<<TOK, 256, 0, stream>>>(X, ln1_g + l * DM, ln1_b + l * DM, HN);
        gemm_kernel<0><<<dim3(QKVW / 64, TOK / 64), 256, 0, stream>>>(
            HN, w_qkv + (size_t)l * DM * QKVW, nullptr, nullptr, QKV, TOK, QKVW, DM);
        for (int b = 0; b < B; ++b) {
            qk_kernel<<<dim3(N / 64, N / 64, H), 256, 0, stream>>>(QKV, ATTN, b);
            softmax_mix_kernel<<<N, 256, 0, stream>>>(
                ATTN, re_w + l * H * H, rln_g + l * H, rln_b + l * H);
            pv_kernel<<<dim3(N / 64, H), 256, 0, stream>>>(ATTN, QKV, AO, b);
        }
        gemm_kernel<3><<<dim3(DM / 64, TOK / 64), 256, 0, stream>>>(
            AO, w_out + (size_t)l * DM * DM, b_out + l * DM, X, X, TOK, DM, DM);

        // ---- ffn ----
        ln_kernel<<<TOK, 256, 0, stream>>>(X, ln2_g + l * DM, ln2_b + l * DM, HN);
        gemm_kernel<2><<<dim3(MLP / 64, TOK / 64), 256, 0, stream>>>(
            HN, w1 + (size_t)l * DM * MLP, b1 + l * MLP, nullptr, HID, TOK, MLP, DM);
        float* outp = (l == 3) ? (float*)d_out : X;
        gemm_kernel<4><<<dim3(DM / 64, TOK / 64), 256, 0, stream>>>(
            HID, w2 + (size_t)l * MLP * DM, b2 + l * DM, X, outp, TOK, DM, MLP);
    }
}